// Round 8
// baseline (611.755 us; speedup 1.0000x reference)
//
#include <hip/hip_runtime.h>

#define O_ 3
#define D_ 128
#define V_ 100000
#define B_ 256
#define SLEN_ 20
#define N_ 5120
#define E_ 10240
#define HD_ 1024
#define NREL 6
#define VPAD 100096
#define CC 17.312340490667562f   /* 12*log2(e) */
#define LN2F 0.6931471805599453f

typedef __attribute__((ext_vector_type(8))) short short8;
typedef __attribute__((ext_vector_type(4))) float floatx4;
typedef unsigned short ushort_t;
typedef unsigned int uint32;

__device__ __forceinline__ float b2f(ushort_t u) {
  union { uint32 u; float f; } x; x.u = ((uint32)u) << 16; return x.f;
}
__device__ __forceinline__ ushort_t f2b(float f) {
  union { float f; uint32 u; } x; x.f = f;
  uint32 r = x.u + 0x7FFFu + ((x.u >> 16) & 1u);
  return (ushort_t)(r >> 16);
}
__device__ __forceinline__ float wave_sum(float v) {
#pragma unroll
  for (int m = 1; m < 64; m <<= 1) v += __shfl_xor(v, m);
  return v;
}

// ---------- weight convert: Wt[rel][outcol][k] bf16 (transposed fc_w) ----------
__global__ void k_convert(const float* g1w, const float* g2w, ushort_t* Wt) {
  int wid = blockIdx.x * 4 + (threadIdx.x >> 6);
  int lane = threadIdx.x & 63;
  int rel = wid >> 10, c = wid & 1023;      // 6 rels x 1024 cols
  int l_ = rel / 3, i = rel % 3;
  const float* sw = (l_ ? g2w : g1w) + (size_t)i * D_ * HD_ + c;
  uint32 lo = f2b(sw[(size_t)(2 * lane) * HD_]);
  uint32 hi = f2b(sw[(size_t)(2 * lane + 1) * HD_]);
  ((uint32*)(Wt + (size_t)rel * HD_ * D_ + (size_t)c * D_))[lane] = lo | (hi << 16);
}

// ---------- h_v = normalize(embedding[iid]) : fp32 + bf16 ----------
__global__ void k_hv(const float* emb, const int* iid, float* hv, ushort_t* hvb) {
  int n = blockIdx.x * 4 + (threadIdx.x >> 6);
  int lane = threadIdx.x & 63;
  const float* row = emb + (size_t)iid[n] * D_;
  float2 v = *(const float2*)(row + 2 * lane);
  float ss = wave_sum(v.x * v.x + v.y * v.y);
  float sc = 1.f / fmaxf(sqrtf(ss), 1e-12f);
  float a = v.x * sc, b = v.y * sc;
  *(float2*)(hv + (size_t)n * D_ + 2 * lane) = make_float2(a, b);
  ((uint32*)hvb)[n * 64 + lane] = (uint32)f2b(a) | ((uint32)f2b(b) << 16);
}

// ---------- bb = normalize(embedding) bf16 ----------
__global__ void k_bb(const float* emb, ushort_t* bbn) {
  int v = blockIdx.x * 4 + (threadIdx.x >> 6);
  int lane = threadIdx.x & 63;
  const float* row = emb + (size_t)v * D_;
  float2 x = *(const float2*)(row + 2 * lane);
  float ss = wave_sum(x.x * x.x + x.y * x.y);
  float sc = 1.f / fmaxf(sqrtf(ss), 1e-12f);
  ((uint32*)bbn)[(size_t)v * 64 + lane] =
      (uint32)f2b(x.x * sc) | ((uint32)f2b(x.y * sc) << 16);
}

// ---------- ft = h_v @ W + b  (bf16 MFMA), batched over 6 relations ----------
__global__ void k_ft(const ushort_t* hvb, const ushort_t* Wt,
                     const float* g1b, const float* g2b, ushort_t* ft) {
  int blk = blockIdx.x;                      // rel*640 + rt4*8 + cg
  int rel = blk / 640, rem = blk % 640;
  int rt4 = rem / 8, cg = rem % 8;
  int w = threadIdx.x >> 6, lane = threadIdx.x & 63;
  int rt = rt4 * 4 + w;                      // 16-row tile
  int l_ = rel / 3, i = rel % 3;
  const float* bias = (l_ ? g2b : g1b) + i * HD_ + cg * 128;
  int cl = lane & 15, g = lane >> 4;
  int r0 = rt * 16 + cl;
  short8 a[4];
#pragma unroll
  for (int c = 0; c < 4; c++)
    a[c] = *(const short8*)(hvb + (size_t)r0 * D_ + c * 32 + g * 8);
  const ushort_t* wbase = Wt + (size_t)rel * HD_ * D_ + (size_t)cg * 128 * D_;
  ushort_t* fbase = ft + (size_t)rel * N_ * HD_;
#pragma unroll
  for (int ct = 0; ct < 8; ++ct) {
    floatx4 acc = {0.f, 0.f, 0.f, 0.f};
    int col = ct * 16 + cl;
#pragma unroll
    for (int c = 0; c < 4; c++) {
      short8 b = *(const short8*)(wbase + (size_t)col * D_ + c * 32 + g * 8);
      acc = __builtin_amdgcn_mfma_f32_16x16x32_bf16(a[c], b, acc, 0, 0, 0);
    }
    float bv = bias[col];
    int colg = cg * 128 + col;
#pragma unroll
    for (int j = 0; j < 4; j++) {
      int row = rt * 16 + g * 4 + j;
      fbase[(size_t)row * HD_ + colg] = f2b(acc[j] + bv);
    }
  }
}

// ---------- per-edge: ex = exp(leakyrelu(pi . (ft_s*ft_d))), den[dst]+=ex ----------
__global__ void k_edge1(const ushort_t* ft, const int* src, const int* dst,
                        const float* g1pi, const float* g2pi,
                        float* ex, float* den) {
  int wid = (int)((blockIdx.x * (size_t)blockDim.x + threadIdx.x) >> 6);
  int lane = threadIdx.x & 63;
  int rel = wid / E_, e = wid % E_;
  int l_ = rel / 3, i = rel % 3;
  const int* sA = (l_ ? dst : src) + (size_t)i * E_;
  const int* dA = (l_ ? src : dst) + (size_t)i * E_;
  int s = sA[e], d = dA[e];
  const float* pi = (l_ ? g2pi : g1pi) + i * HD_;
  const ushort_t* fs = ft + ((size_t)rel * N_ + s) * HD_ + lane * 16;
  const ushort_t* fd = ft + ((size_t)rel * N_ + d) * HD_ + lane * 16;
  short8 s0 = *(const short8*)fs, s1 = *(const short8*)(fs + 8);
  short8 d0 = *(const short8*)fd, d1 = *(const short8*)(fd + 8);
  float t = 0.f;
#pragma unroll
  for (int j = 0; j < 8; j++)
    t += b2f((ushort_t)s0[j]) * b2f((ushort_t)d0[j]) * pi[lane * 16 + j];
#pragma unroll
  for (int j = 0; j < 8; j++)
    t += b2f((ushort_t)s1[j]) * b2f((ushort_t)d1[j]) * pi[lane * 16 + 8 + j];
  t = wave_sum(t);
  float lv = t > 0.f ? t : 0.2f * t;
  float exv = __expf(lv);
  if (lane == 0) {
    ex[(size_t)rel * E_ + e] = exv;
    atomicAdd(den + (size_t)rel * N_ + d, exv);
  }
}

// ---------- bucketed CSR: per-dst edge lists (cap 32) ----------
__global__ void k_csr(const int* src, const int* dst, int* cnt, int* slots) {
  int t = blockIdx.x * 256 + threadIdx.x;
  if (t >= NREL * E_) return;
  int rel = t / E_, e = t % E_;
  int l_ = rel / 3, i = rel % 3;
  const int* dA = (l_ ? src : dst) + (size_t)i * E_;
  int d = dA[e];
  int slot = atomicAdd(cnt + (size_t)rel * N_ + d, 1);
  if (slot < 32) slots[((size_t)rel * N_ + d) * 32 + slot] = e;
}

// ---------- per-dst gather: out = sum a*ft[s]; then head-max -> mh[n][128] ----------
__global__ __launch_bounds__(128) void k_nodeout(
    const ushort_t* ft, const float* ex, const float* den,
    const int* cnt, const int* slots, const int* src, const int* dst, float* mh) {
  int blk = blockIdx.x;
  int rel = blk / N_, n = blk % N_;
  int t = threadIdx.x;
  int l_ = rel / 3, i = rel % 3;
  const int* sA = (l_ ? dst : src) + (size_t)i * E_;
  int c = cnt[(size_t)rel * N_ + n]; if (c > 32) c = 32;
  float dn = den[(size_t)rel * N_ + n];
  float acc[8] = {0, 0, 0, 0, 0, 0, 0, 0};
  for (int j = 0; j < c; j++) {
    int e = slots[((size_t)rel * N_ + n) * 32 + j];
    float a = ex[(size_t)rel * E_ + e] / dn;
    int s = sA[e];
    short8 v = *(const short8*)(ft + ((size_t)rel * N_ + s) * HD_ + t * 8);
#pragma unroll
    for (int q = 0; q < 8; q++) acc[q] += a * b2f((ushort_t)v[q]);
  }
  __shared__ float sm[HD_];
#pragma unroll
  for (int q = 0; q < 8; q++) sm[t * 8 + q] = acc[q];
  __syncthreads();
  float m = sm[t];
#pragma unroll
  for (int h = 1; h < 8; h++) m = fmaxf(m, sm[h * 128 + t]);
  mh[((size_t)rel * N_ + n) * D_ + t] = m;
}

// ---------- h = normalize(2*h_v + mh_gat1 + mh_gat2) per order ----------
__global__ void k_combine(const float* hv, const float* mh, float* h) {
  int idx = blockIdx.x * 4 + (threadIdx.x >> 6);   // o*N + n
  int lane = threadIdx.x & 63;
  int o = idx / N_, n = idx % N_;
  float2 hvv = *(const float2*)(hv + (size_t)n * D_ + 2 * lane);
  const float* m1 = mh + ((size_t)o * N_ + n) * D_ + 2 * lane;
  const float* m2 = mh + ((size_t)(3 + o) * N_ + n) * D_ + 2 * lane;
  float v0 = 2.f * hvv.x + m1[0] + m2[0];
  float v1 = 2.f * hvv.y + m1[1] + m2[1];
  float ss = wave_sum(v0 * v0 + v1 * v1);
  float sc = 1.f / fmaxf(sqrtf(ss), 1e-12f);
  *(float2*)(h + ((size_t)o * N_ + n) * D_ + 2 * lane) = make_float2(v0 * sc, v1 * sc);
}

// ---------- PosAggregator coef: coef[n] = <tanh([h,hp]@q_w), h_r> ----------
__global__ __launch_bounds__(128) void k_pa(
    const float* h, const float* pos, const float* qw,
    const int* pid, const int* tidv, const int* aggd, const float* tgt, float* coef) {
  int o = blockIdx.x / 320, ng = blockIdx.x % 320;
  int n0 = ng * 16, t = threadIdx.x;
  __shared__ float cat[16][256];
  for (int p = t; p < 4096; p += 128) {
    int nn = p >> 8, f = p & 255;
    int n = n0 + nn;
    cat[nn][f] = (f < 128) ? h[((size_t)o * N_ + n) * D_ + f]
                           : pos[(size_t)pid[n] * D_ + (f - 128)];
  }
  __syncthreads();
  float acc[16];
#pragma unroll
  for (int nn = 0; nn < 16; nn++) acc[nn] = 0.f;
  const float* qwo = qw + (size_t)o * 256 * D_;
#pragma unroll 4
  for (int f = 0; f < 256; ++f) {
    float wv = qwo[(size_t)f * D_ + t];
#pragma unroll
    for (int nn = 0; nn < 16; nn++) acc[nn] += cat[nn][f] * wv;
  }
  __shared__ float red[16][129];
#pragma unroll
  for (int nn = 0; nn < 16; nn++) {
    int n = n0 + nn;
    float hr = tgt[(size_t)tidv[aggd[n]] * D_ + t];
    red[nn][t] = tanhf(acc[nn]) * hr;
  }
  __syncthreads();
  int nn = t >> 3, seg = t & 7;
  float ps = 0.f;
#pragma unroll
  for (int q = 0; q < 16; q++) ps += red[nn][seg * 16 + q];
  __shared__ float red2[16][8];
  red2[nn][seg] = ps;
  __syncthreads();
  if (t < 16) {
    float c2 = 0.f;
#pragma unroll
    for (int s = 0; s < 8; s++) c2 += red2[t][s];
    coef[(size_t)o * N_ + n0 + t] = c2;
  }
}

// ---------- session agg + fc_sr + normalize -> sr_b bf16 [o*256+b][128] ----------
__global__ __launch_bounds__(128) void k_agg(
    const float* h, const float* coef, const float* srw,
    const int* lasti, ushort_t* srb) {
  int o = blockIdx.x / B_, b = blockIdx.x % B_;
  int t = threadIdx.x;
  __shared__ float cat[256];
  int li = lasti[b];
  cat[t] = h[((size_t)o * N_ + li) * D_ + t];
  float x = 0.f;
#pragma unroll
  for (int j = 0; j < SLEN_; j++) {
    int n = b * SLEN_ + j;
    x += h[((size_t)o * N_ + n) * D_ + t] * coef[(size_t)o * N_ + n];
  }
  cat[128 + t] = x;
  __syncthreads();
  const float* wo = srw + (size_t)o * 256 * D_;
  float acc = 0.f;
#pragma unroll 4
  for (int f = 0; f < 256; ++f) acc += cat[f] * wo[(size_t)f * D_ + t];
  __shared__ float rr[128];
  rr[t] = acc * acc;
  __syncthreads();
  for (int s = 64; s > 0; s >>= 1) {
    if (t < s) rr[t] += rr[t + s];
    __syncthreads();
  }
  float sc = 1.f / fmaxf(sqrtf(rr[0]), 1e-12f);
  srb[(size_t)(o * B_ + b) * D_ + t] = f2b(acc * sc);
}

// ---------- LDS staging for bb chunks (XOR swizzle both sides) ----------
__device__ __forceinline__ void stage_bb(ushort_t* smem, const ushort_t* bbn,
                                         size_t vbase, int tid) {
  const char* chunk = (const char*)(bbn + vbase * D_);
#pragma unroll
  for (int it = 0; it < 8; ++it) {
    int lin = (it * 256 + tid) * 16;
    int row = lin >> 8;
    int dsto = lin ^ ((row & 7) << 4);
    *(short8*)((char*)smem + dsto) = *(const short8*)(chunk + lin);
  }
}
__device__ __forceinline__ short8 read_bb(const ushort_t* smem, int vl, int c, int g) {
  int byte = vl * 256 + c * 64 + (g << 4);
  byte ^= (vl & 7) << 4;
  return *(const short8*)((const char*)smem + byte);
}
__device__ __forceinline__ short8 read_sr(const ushort_t* srb, int tile, int cl, int c, int g) {
  return *(const short8*)(srb + (size_t)(tile * 16 + cl) * D_ + c * 32 + g * 8);
}

// ---------- pass 1: den[r] = sum_v exp(12 * sr[r].bb[v]) ----------
__global__ __launch_bounds__(256) void k_den(const ushort_t* srb, const ushort_t* bbn,
                                             float* den) {
  __shared__ ushort_t smem[128 * 128];
  int tid = threadIdx.x, w = tid >> 6, lane = tid & 63;
  size_t vbase = (size_t)blockIdx.x * 128;
  stage_bb(smem, bbn, vbase, tid);
  __syncthreads();
  int g = lane >> 4, cl = lane & 15;
  float rs[12][4];
#pragma unroll
  for (int a = 0; a < 12; a++)
#pragma unroll
    for (int j = 0; j < 4; j++) rs[a][j] = 0.f;
#pragma unroll
  for (int grp = 0; grp < 6; ++grp) {
    int t0 = w * 12 + grp * 2;
    short8 a0[4], a1[4];
#pragma unroll
    for (int c = 0; c < 4; c++) {
      a0[c] = read_sr(srb, t0, cl, c, g);
      a1[c] = read_sr(srb, t0 + 1, cl, c, g);
    }
#pragma unroll
    for (int vt = 0; vt < 8; ++vt) {
      int vl = vt * 16 + cl;
      floatx4 acc0 = {0.f, 0.f, 0.f, 0.f}, acc1 = {0.f, 0.f, 0.f, 0.f};
#pragma unroll
      for (int c = 0; c < 4; c++) {
        short8 bf = read_bb(smem, vl, c, g);
        acc0 = __builtin_amdgcn_mfma_f32_16x16x32_bf16(a0[c], bf, acc0, 0, 0, 0);
        acc1 = __builtin_amdgcn_mfma_f32_16x16x32_bf16(a1[c], bf, acc1, 0, 0, 0);
      }
      bool valid = (vbase + vl) < V_;
#pragma unroll
      for (int j = 0; j < 4; j++) {
        rs[grp * 2][j]     += valid ? exp2f(CC * acc0[j]) : 0.f;
        rs[grp * 2 + 1][j] += valid ? exp2f(CC * acc1[j]) : 0.f;
      }
    }
  }
#pragma unroll
  for (int a = 0; a < 12; a++) {
#pragma unroll
    for (int j = 0; j < 4; j++) {
      float v = rs[a][j];
      v += __shfl_xor(v, 1); v += __shfl_xor(v, 2);
      v += __shfl_xor(v, 4); v += __shfl_xor(v, 8);
      if (cl == 0) atomicAdd(den + (w * 12 + a) * 16 + g * 4 + j, v);
    }
  }
}

// ---------- w[r] = softmax(alpha)[o] / den[r] ----------
__global__ void k_w(const float* alpha, const float* den, float* w) {
  int r = blockIdx.x * 256 + threadIdx.x;
  if (r >= 768) return;
  float a0 = alpha[0], a1 = alpha[1], a2 = alpha[2];
  float m = fmaxf(a0, fmaxf(a1, a2));
  float e0 = __expf(a0 - m), e1 = __expf(a1 - m), e2 = __expf(a2 - m);
  float s = e0 + e1 + e2;
  float al = (r < 256 ? e0 : (r < 512 ? e1 : e2)) / s;
  w[r] = al / den[r];
}

// ---------- pass 2: out[b][v] = log(sum_o w[o,b]*exp(12*sr.bb)) ----------
__global__ __launch_bounds__(256) void k_out(const ushort_t* srb, const ushort_t* bbn,
                                             const float* w, float* out) {
  __shared__ ushort_t smem[128 * 128];
  int tid = threadIdx.x, wv_ = tid >> 6, lane = tid & 63;
  size_t vbase = (size_t)blockIdx.x * 128;
  stage_bb(smem, bbn, vbase, tid);
  __syncthreads();
  int g = lane >> 4, cl = lane & 15;
#pragma unroll
  for (int q = 0; q < 4; ++q) {
    int bt = wv_ * 4 + q;
    short8 a0[4], a1[4], a2[4];
#pragma unroll
    for (int c = 0; c < 4; c++) {
      a0[c] = read_sr(srb, bt, cl, c, g);
      a1[c] = read_sr(srb, 16 + bt, cl, c, g);
      a2[c] = read_sr(srb, 32 + bt, cl, c, g);
    }
    float w0[4], w1[4], w2[4];
#pragma unroll
    for (int j = 0; j < 4; j++) {
      int b = bt * 16 + g * 4 + j;
      w0[j] = w[b]; w1[j] = w[256 + b]; w2[j] = w[512 + b];
    }
#pragma unroll
    for (int vt = 0; vt < 8; ++vt) {
      int vl = vt * 16 + cl;
      floatx4 acc0 = {0.f, 0.f, 0.f, 0.f}, acc1 = {0.f, 0.f, 0.f, 0.f},
              acc2 = {0.f, 0.f, 0.f, 0.f};
#pragma unroll
      for (int c = 0; c < 4; c++) {
        short8 bf = read_bb(smem, vl, c, g);
        acc0 = __builtin_amdgcn_mfma_f32_16x16x32_bf16(a0[c], bf, acc0, 0, 0, 0);
        acc1 = __builtin_amdgcn_mfma_f32_16x16x32_bf16(a1[c], bf, acc1, 0, 0, 0);
        acc2 = __builtin_amdgcn_mfma_f32_16x16x32_bf16(a2[c], bf, acc2, 0, 0, 0);
      }
      size_t v = vbase + vl;
      if (v < V_) {
#pragma unroll
        for (int j = 0; j < 4; j++) {
          float s = w0[j] * exp2f(CC * acc0[j]) + w1[j] * exp2f(CC * acc1[j]) +
                    w2[j] * exp2f(CC * acc2[j]);
          int b = bt * 16 + g * 4 + j;
          out[(size_t)b * V_ + v] = log2f(s) * LN2F;
        }
      }
    }
  }
}

extern "C" void kernel_launch(void* const* d_in, const int* in_sizes, int n_in,
                              void* d_out, int out_size, void* d_ws, size_t ws_size,
                              hipStream_t stream) {
  const float* emb   = (const float*)d_in[0];
  const float* pos   = (const float*)d_in[1];
  const float* tgt   = (const float*)d_in[2];
  const float* g1w   = (const float*)d_in[3];
  const float* g1b   = (const float*)d_in[4];
  const float* g1pi  = (const float*)d_in[5];
  const float* g2w   = (const float*)d_in[6];
  const float* g2b   = (const float*)d_in[7];
  const float* g2pi  = (const float*)d_in[8];
  const float* qw    = (const float*)d_in[9];
  const float* srw   = (const float*)d_in[10];
  const float* alpha = (const float*)d_in[11];
  const int* iid     = (const int*)d_in[12];
  const int* src     = (const int*)d_in[13];
  const int* dst     = (const int*)d_in[14];
  const int* aggd    = (const int*)d_in[15];
  const int* pid     = (const int*)d_in[16];
  const int* tidv    = (const int*)d_in[17];
  const int* lasti   = (const int*)d_in[18];
  float* out = (float*)d_out;

  char* p = (char*)d_ws;
  auto alloc = [&](size_t bytes) {
    char* r = p;
    p += (bytes + 255) & ~(size_t)255;
    return r;
  };
  float* den_att = (float*)alloc((size_t)NREL * N_ * 4);   // zeroed
  int*   cnt     = (int*)  alloc((size_t)NREL * N_ * 4);   // zeroed
  float* den_sm  = (float*)alloc(768 * 4);                 // zeroed
  char* zero_end = p;
  float* hv    = (float*)alloc((size_t)N_ * D_ * 4);
  float* h     = (float*)alloc((size_t)O_ * N_ * D_ * 4);
  float* coef  = (float*)alloc((size_t)O_ * N_ * 4);
  float* mh    = (float*)alloc((size_t)NREL * N_ * D_ * 4);
  float* ex    = (float*)alloc((size_t)NREL * E_ * 4);
  float* w_sm  = (float*)alloc(768 * 4);
  int*   slots = (int*)  alloc((size_t)NREL * N_ * 32 * 4);
  ushort_t* hvb = (ushort_t*)alloc((size_t)N_ * D_ * 2);
  ushort_t* Wt  = (ushort_t*)alloc((size_t)NREL * HD_ * D_ * 2);
  ushort_t* ft  = (ushort_t*)alloc((size_t)NREL * N_ * HD_ * 2);
  ushort_t* srb = (ushort_t*)alloc((size_t)768 * D_ * 2);
  ushort_t* bbn = (ushort_t*)alloc((size_t)VPAD * D_ * 2);

  hipMemsetAsync(d_ws, 0, (size_t)(zero_end - (char*)d_ws), stream);

  k_convert<<<1536, 256, 0, stream>>>(g1w, g2w, Wt);
  k_hv<<<N_ / 4, 256, 0, stream>>>(emb, iid, hv, hvb);
  k_ft<<<NREL * 640, 256, 0, stream>>>(hvb, Wt, g1b, g2b, ft);
  k_edge1<<<NREL * E_ / 4, 256, 0, stream>>>(ft, src, dst, g1pi, g2pi, ex, den_att);
  k_csr<<<NREL * E_ / 256, 256, 0, stream>>>(src, dst, cnt, slots);
  k_nodeout<<<NREL * N_, 128, 0, stream>>>(ft, ex, den_att, cnt, slots, src, dst, mh);
  k_combine<<<O_ * N_ / 4, 256, 0, stream>>>(hv, mh, h);
  k_pa<<<O_ * (N_ / 16), 128, 0, stream>>>(h, pos, qw, pid, tidv, aggd, tgt, coef);
  k_agg<<<O_ * B_, 128, 0, stream>>>(h, coef, srw, lasti, srb);
  k_bb<<<V_ / 4, 256, 0, stream>>>(emb, bbn);
  k_den<<<VPAD / 128, 256, 0, stream>>>(srb, bbn, den_sm);
  k_w<<<3, 256, 0, stream>>>(alpha, den_sm, w_sm);
  k_out<<<VPAD / 128, 256, 0, stream>>>(srb, bbn, w_sm, out);
}

// Round 9
// 552.239 us; speedup vs baseline: 1.1078x; 1.1078x over previous
//
#include <hip/hip_runtime.h>

#define O_ 3
#define D_ 128
#define V_ 100000
#define B_ 256
#define SLEN_ 20
#define N_ 5120
#define E_ 10240
#define HD_ 1024
#define NREL 6
#define VPAD 100096
#define CC 17.312340490667562f   /* 12*log2(e) */
#define LN2F 0.6931471805599453f

typedef __attribute__((ext_vector_type(8))) short short8;
typedef __attribute__((ext_vector_type(4))) float floatx4;
typedef unsigned short ushort_t;
typedef unsigned int uint32;

__device__ __forceinline__ float b2f(ushort_t u) {
  union { uint32 u; float f; } x; x.u = ((uint32)u) << 16; return x.f;
}
__device__ __forceinline__ ushort_t f2b(float f) {
  union { float f; uint32 u; } x; x.f = f;
  uint32 r = x.u + 0x7FFFu + ((x.u >> 16) & 1u);
  return (ushort_t)(r >> 16);
}
__device__ __forceinline__ float wave_sum(float v) {
#pragma unroll
  for (int m = 1; m < 64; m <<= 1) v += __shfl_xor(v, m);
  return v;
}

// ---------- weight convert: Wt[rel][outcol][k] bf16 (transposed fc_w) ----------
__global__ void k_convert(const float* g1w, const float* g2w, ushort_t* Wt) {
  int wid = blockIdx.x * 4 + (threadIdx.x >> 6);
  int lane = threadIdx.x & 63;
  int rel = wid >> 10, c = wid & 1023;      // 6 rels x 1024 cols
  int l_ = rel / 3, i = rel % 3;
  const float* sw = (l_ ? g2w : g1w) + (size_t)i * D_ * HD_ + c;
  uint32 lo = f2b(sw[(size_t)(2 * lane) * HD_]);
  uint32 hi = f2b(sw[(size_t)(2 * lane + 1) * HD_]);
  ((uint32*)(Wt + (size_t)rel * HD_ * D_ + (size_t)c * D_))[lane] = lo | (hi << 16);
}

// ---------- h_v = normalize(embedding[iid]) : fp32 + bf16 ----------
__global__ void k_hv(const float* emb, const int* iid, float* hv, ushort_t* hvb) {
  int n = blockIdx.x * 4 + (threadIdx.x >> 6);
  int lane = threadIdx.x & 63;
  const float* row = emb + (size_t)iid[n] * D_;
  float2 v = *(const float2*)(row + 2 * lane);
  float ss = wave_sum(v.x * v.x + v.y * v.y);
  float sc = 1.f / fmaxf(sqrtf(ss), 1e-12f);
  float a = v.x * sc, b = v.y * sc;
  *(float2*)(hv + (size_t)n * D_ + 2 * lane) = make_float2(a, b);
  ((uint32*)hvb)[n * 64 + lane] = (uint32)f2b(a) | ((uint32)f2b(b) << 16);
}

// ---------- bb = normalize(embedding) bf16 ----------
__global__ void k_bb(const float* emb, ushort_t* bbn) {
  int v = blockIdx.x * 4 + (threadIdx.x >> 6);
  int lane = threadIdx.x & 63;
  const float* row = emb + (size_t)v * D_;
  float2 x = *(const float2*)(row + 2 * lane);
  float ss = wave_sum(x.x * x.x + x.y * x.y);
  float sc = 1.f / fmaxf(sqrtf(ss), 1e-12f);
  ((uint32*)bbn)[(size_t)v * 64 + lane] =
      (uint32)f2b(x.x * sc) | ((uint32)f2b(x.y * sc) << 16);
}

// ---------- ft = h_v @ W + b  (bf16 MFMA), batched over 6 relations ----------
__global__ void k_ft(const ushort_t* hvb, const ushort_t* Wt,
                     const float* g1b, const float* g2b, ushort_t* ft) {
  int blk = blockIdx.x;                      // rel*640 + rt4*8 + cg
  int rel = blk / 640, rem = blk % 640;
  int rt4 = rem / 8, cg = rem % 8;
  int w = threadIdx.x >> 6, lane = threadIdx.x & 63;
  int rt = rt4 * 4 + w;                      // 16-row tile
  int l_ = rel / 3, i = rel % 3;
  const float* bias = (l_ ? g2b : g1b) + i * HD_ + cg * 128;
  int cl = lane & 15, g = lane >> 4;
  int r0 = rt * 16 + cl;
  short8 a[4];
#pragma unroll
  for (int c = 0; c < 4; c++)
    a[c] = *(const short8*)(hvb + (size_t)r0 * D_ + c * 32 + g * 8);
  const ushort_t* wbase = Wt + (size_t)rel * HD_ * D_ + (size_t)cg * 128 * D_;
  ushort_t* fbase = ft + (size_t)rel * N_ * HD_;
#pragma unroll
  for (int ct = 0; ct < 8; ++ct) {
    floatx4 acc = {0.f, 0.f, 0.f, 0.f};
    int col = ct * 16 + cl;
#pragma unroll
    for (int c = 0; c < 4; c++) {
      short8 b = *(const short8*)(wbase + (size_t)col * D_ + c * 32 + g * 8);
      acc = __builtin_amdgcn_mfma_f32_16x16x32_bf16(a[c], b, acc, 0, 0, 0);
    }
    float bv = bias[col];
    int colg = cg * 128 + col;
#pragma unroll
    for (int j = 0; j < 4; j++) {
      int row = rt * 16 + g * 4 + j;
      fbase[(size_t)row * HD_ + colg] = f2b(acc[j] + bv);
    }
  }
}

// ---------- per-edge: ex = exp(leakyrelu(pi . (ft_s*ft_d))), den[dst]+=ex ----------
__global__ void k_edge1(const ushort_t* ft, const int* src, const int* dst,
                        const float* g1pi, const float* g2pi,
                        float* ex, float* den) {
  int wid = (int)((blockIdx.x * (size_t)blockDim.x + threadIdx.x) >> 6);
  int lane = threadIdx.x & 63;
  int rel = wid / E_, e = wid % E_;
  int l_ = rel / 3, i = rel % 3;
  const int* sA = (l_ ? dst : src) + (size_t)i * E_;
  const int* dA = (l_ ? src : dst) + (size_t)i * E_;
  int s = sA[e], d = dA[e];
  const float* pi = (l_ ? g2pi : g1pi) + i * HD_;
  const ushort_t* fs = ft + ((size_t)rel * N_ + s) * HD_ + lane * 16;
  const ushort_t* fd = ft + ((size_t)rel * N_ + d) * HD_ + lane * 16;
  short8 s0 = *(const short8*)fs, s1 = *(const short8*)(fs + 8);
  short8 d0 = *(const short8*)fd, d1 = *(const short8*)(fd + 8);
  float t = 0.f;
#pragma unroll
  for (int j = 0; j < 8; j++)
    t += b2f((ushort_t)s0[j]) * b2f((ushort_t)d0[j]) * pi[lane * 16 + j];
#pragma unroll
  for (int j = 0; j < 8; j++)
    t += b2f((ushort_t)s1[j]) * b2f((ushort_t)d1[j]) * pi[lane * 16 + 8 + j];
  t = wave_sum(t);
  float lv = t > 0.f ? t : 0.2f * t;
  float exv = __expf(lv);
  if (lane == 0) {
    ex[(size_t)rel * E_ + e] = exv;
    atomicAdd(den + (size_t)rel * N_ + d, exv);
  }
}

// ---------- bucketed CSR: per-dst edge lists (cap 32) ----------
__global__ void k_csr(const int* src, const int* dst, int* cnt, int* slots) {
  int t = blockIdx.x * 256 + threadIdx.x;
  if (t >= NREL * E_) return;
  int rel = t / E_, e = t % E_;
  int l_ = rel / 3, i = rel % 3;
  const int* dA = (l_ ? src : dst) + (size_t)i * E_;
  int d = dA[e];
  int slot = atomicAdd(cnt + (size_t)rel * N_ + d, 1);
  if (slot < 32) slots[((size_t)rel * N_ + d) * 32 + slot] = e;
}

// ---------- per-dst gather: out = sum a*ft[s]; then head-max -> mh[n][128] ----------
__global__ __launch_bounds__(128) void k_nodeout(
    const ushort_t* ft, const float* ex, const float* den,
    const int* cnt, const int* slots, const int* src, const int* dst, float* mh) {
  int blk = blockIdx.x;
  int rel = blk / N_, n = blk % N_;
  int t = threadIdx.x;
  int l_ = rel / 3, i = rel % 3;
  const int* sA = (l_ ? dst : src) + (size_t)i * E_;
  int c = cnt[(size_t)rel * N_ + n]; if (c > 32) c = 32;
  float dn = den[(size_t)rel * N_ + n];
  float acc[8] = {0, 0, 0, 0, 0, 0, 0, 0};
  for (int j = 0; j < c; j++) {
    int e = slots[((size_t)rel * N_ + n) * 32 + j];
    float a = ex[(size_t)rel * E_ + e] / dn;
    int s = sA[e];
    short8 v = *(const short8*)(ft + ((size_t)rel * N_ + s) * HD_ + t * 8);
#pragma unroll
    for (int q = 0; q < 8; q++) acc[q] += a * b2f((ushort_t)v[q]);
  }
  __shared__ float sm[HD_];
#pragma unroll
  for (int q = 0; q < 8; q++) sm[t * 8 + q] = acc[q];
  __syncthreads();
  float m = sm[t];
#pragma unroll
  for (int h = 1; h < 8; h++) m = fmaxf(m, sm[h * 128 + t]);
  mh[((size_t)rel * N_ + n) * D_ + t] = m;
}

// ---------- h = normalize(2*h_v + mh_gat1 + mh_gat2) per order ----------
__global__ void k_combine(const float* hv, const float* mh, float* h) {
  int idx = blockIdx.x * 4 + (threadIdx.x >> 6);   // o*N + n
  int lane = threadIdx.x & 63;
  int o = idx / N_, n = idx % N_;
  float2 hvv = *(const float2*)(hv + (size_t)n * D_ + 2 * lane);
  const float* m1 = mh + ((size_t)o * N_ + n) * D_ + 2 * lane;
  const float* m2 = mh + ((size_t)(3 + o) * N_ + n) * D_ + 2 * lane;
  float v0 = 2.f * hvv.x + m1[0] + m2[0];
  float v1 = 2.f * hvv.y + m1[1] + m2[1];
  float ss = wave_sum(v0 * v0 + v1 * v1);
  float sc = 1.f / fmaxf(sqrtf(ss), 1e-12f);
  *(float2*)(h + ((size_t)o * N_ + n) * D_ + 2 * lane) = make_float2(v0 * sc, v1 * sc);
}

// ---------- PosAggregator coef: coef[n] = <tanh([h,hp]@q_w), h_r> ----------
__global__ __launch_bounds__(128) void k_pa(
    const float* h, const float* pos, const float* qw,
    const int* pid, const int* tidv, const int* aggd, const float* tgt, float* coef) {
  int o = blockIdx.x / 320, ng = blockIdx.x % 320;
  int n0 = ng * 16, t = threadIdx.x;
  __shared__ float cat[16][256];
  for (int p = t; p < 4096; p += 128) {
    int nn = p >> 8, f = p & 255;
    int n = n0 + nn;
    cat[nn][f] = (f < 128) ? h[((size_t)o * N_ + n) * D_ + f]
                           : pos[(size_t)pid[n] * D_ + (f - 128)];
  }
  __syncthreads();
  float acc[16];
#pragma unroll
  for (int nn = 0; nn < 16; nn++) acc[nn] = 0.f;
  const float* qwo = qw + (size_t)o * 256 * D_;
#pragma unroll 4
  for (int f = 0; f < 256; ++f) {
    float wv = qwo[(size_t)f * D_ + t];
#pragma unroll
    for (int nn = 0; nn < 16; nn++) acc[nn] += cat[nn][f] * wv;
  }
  __shared__ float red[16][129];
#pragma unroll
  for (int nn = 0; nn < 16; nn++) {
    int n = n0 + nn;
    float hr = tgt[(size_t)tidv[aggd[n]] * D_ + t];
    red[nn][t] = tanhf(acc[nn]) * hr;
  }
  __syncthreads();
  int nn = t >> 3, seg = t & 7;
  float ps = 0.f;
#pragma unroll
  for (int q = 0; q < 16; q++) ps += red[nn][seg * 16 + q];
  __shared__ float red2[16][8];
  red2[nn][seg] = ps;
  __syncthreads();
  if (t < 16) {
    float c2 = 0.f;
#pragma unroll
    for (int s = 0; s < 8; s++) c2 += red2[t][s];
    coef[(size_t)o * N_ + n0 + t] = c2;
  }
}

// ---------- session agg + fc_sr + normalize -> sr_b bf16 [o*256+b][128] ----------
__global__ __launch_bounds__(128) void k_agg(
    const float* h, const float* coef, const float* srw,
    const int* lasti, ushort_t* srb) {
  int o = blockIdx.x / B_, b = blockIdx.x % B_;
  int t = threadIdx.x;
  __shared__ float cat[256];
  int li = lasti[b];
  cat[t] = h[((size_t)o * N_ + li) * D_ + t];
  float x = 0.f;
#pragma unroll
  for (int j = 0; j < SLEN_; j++) {
    int n = b * SLEN_ + j;
    x += h[((size_t)o * N_ + n) * D_ + t] * coef[(size_t)o * N_ + n];
  }
  cat[128 + t] = x;
  __syncthreads();
  const float* wo = srw + (size_t)o * 256 * D_;
  float acc = 0.f;
#pragma unroll 4
  for (int f = 0; f < 256; ++f) acc += cat[f] * wo[(size_t)f * D_ + t];
  __shared__ float rr[128];
  rr[t] = acc * acc;
  __syncthreads();
  for (int s = 64; s > 0; s >>= 1) {
    if (t < s) rr[t] += rr[t + s];
    __syncthreads();
  }
  float sc = 1.f / fmaxf(sqrtf(rr[0]), 1e-12f);
  srb[(size_t)(o * B_ + b) * D_ + t] = f2b(acc * sc);
}

// ---------- LDS staging for bb chunks (XOR swizzle both sides) ----------
__device__ __forceinline__ void stage_bb(ushort_t* smem, const ushort_t* bbn,
                                         size_t vbase, int tid) {
  const char* chunk = (const char*)(bbn + vbase * D_);
#pragma unroll
  for (int it = 0; it < 8; ++it) {
    int lin = (it * 256 + tid) * 16;
    int row = lin >> 8;
    int dsto = lin ^ ((row & 7) << 4);
    *(short8*)((char*)smem + dsto) = *(const short8*)(chunk + lin);
  }
}
__device__ __forceinline__ short8 read_bb(const ushort_t* smem, int vl, int c, int g) {
  int byte = vl * 256 + c * 64 + (g << 4);
  byte ^= (vl & 7) << 4;
  return *(const short8*)((const char*)smem + byte);
}
__device__ __forceinline__ short8 read_sr(const ushort_t* srb, int tile, int cl, int c, int g) {
  return *(const short8*)(srb + (size_t)(tile * 16 + cl) * D_ + c * 32 + g * 8);
}

#define REDUCE_ROW(rsv, tile)                                      \
  {                                                                \
    _Pragma("unroll")                                              \
    for (int j = 0; j < 4; j++) {                                  \
      float v = rsv[j];                                            \
      v += __shfl_xor(v, 1); v += __shfl_xor(v, 2);                \
      v += __shfl_xor(v, 4); v += __shfl_xor(v, 8);                \
      if (cl == 0) atomicAdd(den + (tile) * 16 + g * 4 + j, v);    \
    }                                                              \
  }

// ---------- pass 1: den[r] = sum_v exp(12 * sr[r].bb[v]) ----------
// grid = (VPAD/128) * 4 row-groups; each wave owns 3 sr-tiles (occupancy fix:
// VGPR 256->~110, blocks/CU 2->5)
__global__ __launch_bounds__(256) void k_den(const ushort_t* srb, const ushort_t* bbn,
                                             float* den) {
  __shared__ ushort_t smem[128 * 128];
  int tid = threadIdx.x, w = tid >> 6, lane = tid & 63;
  int blk = blockIdx.x;
  int rg = blk & 3;
  size_t vbase = (size_t)(blk >> 2) * 128;
  stage_bb(smem, bbn, vbase, tid);
  __syncthreads();
  int g = lane >> 4, cl = lane & 15;
  int t0 = rg * 12 + w * 3;
  short8 a0[4], a1[4], a2[4];
#pragma unroll
  for (int c = 0; c < 4; c++) {
    a0[c] = read_sr(srb, t0, cl, c, g);
    a1[c] = read_sr(srb, t0 + 1, cl, c, g);
    a2[c] = read_sr(srb, t0 + 2, cl, c, g);
  }
  float rs0[4] = {0, 0, 0, 0}, rs1[4] = {0, 0, 0, 0}, rs2[4] = {0, 0, 0, 0};
#pragma unroll
  for (int vt = 0; vt < 8; ++vt) {
    int vl = vt * 16 + cl;
    floatx4 acc0 = {0.f, 0.f, 0.f, 0.f}, acc1 = {0.f, 0.f, 0.f, 0.f},
            acc2 = {0.f, 0.f, 0.f, 0.f};
#pragma unroll
    for (int c = 0; c < 4; c++) {
      short8 bf = read_bb(smem, vl, c, g);
      acc0 = __builtin_amdgcn_mfma_f32_16x16x32_bf16(a0[c], bf, acc0, 0, 0, 0);
      acc1 = __builtin_amdgcn_mfma_f32_16x16x32_bf16(a1[c], bf, acc1, 0, 0, 0);
      acc2 = __builtin_amdgcn_mfma_f32_16x16x32_bf16(a2[c], bf, acc2, 0, 0, 0);
    }
    bool valid = (vbase + vl) < V_;
#pragma unroll
    for (int j = 0; j < 4; j++) {
      rs0[j] += valid ? exp2f(CC * acc0[j]) : 0.f;
      rs1[j] += valid ? exp2f(CC * acc1[j]) : 0.f;
      rs2[j] += valid ? exp2f(CC * acc2[j]) : 0.f;
    }
  }
  REDUCE_ROW(rs0, t0)
  REDUCE_ROW(rs1, t0 + 1)
  REDUCE_ROW(rs2, t0 + 2)
}

// ---------- w[r] = softmax(alpha)[o] / den[r] ----------
__global__ void k_w(const float* alpha, const float* den, float* w) {
  int r = blockIdx.x * 256 + threadIdx.x;
  if (r >= 768) return;
  float a0 = alpha[0], a1 = alpha[1], a2 = alpha[2];
  float m = fmaxf(a0, fmaxf(a1, a2));
  float e0 = __expf(a0 - m), e1 = __expf(a1 - m), e2 = __expf(a2 - m);
  float s = e0 + e1 + e2;
  float al = (r < 256 ? e0 : (r < 512 ? e1 : e2)) / s;
  w[r] = al / den[r];
}

// ---------- pass 2: out[b][v] = log(sum_o w[o,b]*exp(12*sr.bb)) ----------
// grid = (VPAD/128) * 4 b-tile-groups; each wave owns 1 b-tile x 3 orders
__global__ __launch_bounds__(256) void k_out(const ushort_t* srb, const ushort_t* bbn,
                                             const float* w, float* out) {
  __shared__ ushort_t smem[128 * 128];
  int tid = threadIdx.x, wv_ = tid >> 6, lane = tid & 63;
  int blk = blockIdx.x;
  int qg = blk & 3;
  size_t vbase = (size_t)(blk >> 2) * 128;
  stage_bb(smem, bbn, vbase, tid);
  __syncthreads();
  int g = lane >> 4, cl = lane & 15;
  int bt = qg * 4 + wv_;
  short8 a0[4], a1[4], a2[4];
#pragma unroll
  for (int c = 0; c < 4; c++) {
    a0[c] = read_sr(srb, bt, cl, c, g);
    a1[c] = read_sr(srb, 16 + bt, cl, c, g);
    a2[c] = read_sr(srb, 32 + bt, cl, c, g);
  }
  float w0[4], w1[4], w2[4];
#pragma unroll
  for (int j = 0; j < 4; j++) {
    int b = bt * 16 + g * 4 + j;
    w0[j] = w[b]; w1[j] = w[256 + b]; w2[j] = w[512 + b];
  }
#pragma unroll
  for (int vt = 0; vt < 8; ++vt) {
    int vl = vt * 16 + cl;
    floatx4 acc0 = {0.f, 0.f, 0.f, 0.f}, acc1 = {0.f, 0.f, 0.f, 0.f},
            acc2 = {0.f, 0.f, 0.f, 0.f};
#pragma unroll
    for (int c = 0; c < 4; c++) {
      short8 bf = read_bb(smem, vl, c, g);
      acc0 = __builtin_amdgcn_mfma_f32_16x16x32_bf16(a0[c], bf, acc0, 0, 0, 0);
      acc1 = __builtin_amdgcn_mfma_f32_16x16x32_bf16(a1[c], bf, acc1, 0, 0, 0);
      acc2 = __builtin_amdgcn_mfma_f32_16x16x32_bf16(a2[c], bf, acc2, 0, 0, 0);
    }
    size_t v = vbase + vl;
    if (v < V_) {
#pragma unroll
      for (int j = 0; j < 4; j++) {
        float s = w0[j] * exp2f(CC * acc0[j]) + w1[j] * exp2f(CC * acc1[j]) +
                  w2[j] * exp2f(CC * acc2[j]);
        int b = bt * 16 + g * 4 + j;
        out[(size_t)b * V_ + v] = log2f(s) * LN2F;
      }
    }
  }
}

extern "C" void kernel_launch(void* const* d_in, const int* in_sizes, int n_in,
                              void* d_out, int out_size, void* d_ws, size_t ws_size,
                              hipStream_t stream) {
  const float* emb   = (const float*)d_in[0];
  const float* pos   = (const float*)d_in[1];
  const float* tgt   = (const float*)d_in[2];
  const float* g1w   = (const float*)d_in[3];
  const float* g1b   = (const float*)d_in[4];
  const float* g1pi  = (const float*)d_in[5];
  const float* g2w   = (const float*)d_in[6];
  const float* g2b   = (const float*)d_in[7];
  const float* g2pi  = (const float*)d_in[8];
  const float* qw    = (const float*)d_in[9];
  const float* srw   = (const float*)d_in[10];
  const float* alpha = (const float*)d_in[11];
  const int* iid     = (const int*)d_in[12];
  const int* src     = (const int*)d_in[13];
  const int* dst     = (const int*)d_in[14];
  const int* aggd    = (const int*)d_in[15];
  const int* pid     = (const int*)d_in[16];
  const int* tidv    = (const int*)d_in[17];
  const int* lasti   = (const int*)d_in[18];
  float* out = (float*)d_out;

  char* p = (char*)d_ws;
  auto alloc = [&](size_t bytes) {
    char* r = p;
    p += (bytes + 255) & ~(size_t)255;
    return r;
  };
  float* den_att = (float*)alloc((size_t)NREL * N_ * 4);   // zeroed
  int*   cnt     = (int*)  alloc((size_t)NREL * N_ * 4);   // zeroed
  float* den_sm  = (float*)alloc(768 * 4);                 // zeroed
  char* zero_end = p;
  float* hv    = (float*)alloc((size_t)N_ * D_ * 4);
  float* h     = (float*)alloc((size_t)O_ * N_ * D_ * 4);
  float* coef  = (float*)alloc((size_t)O_ * N_ * 4);
  float* mh    = (float*)alloc((size_t)NREL * N_ * D_ * 4);
  float* ex    = (float*)alloc((size_t)NREL * E_ * 4);
  float* w_sm  = (float*)alloc(768 * 4);
  int*   slots = (int*)  alloc((size_t)NREL * N_ * 32 * 4);
  ushort_t* hvb = (ushort_t*)alloc((size_t)N_ * D_ * 2);
  ushort_t* Wt  = (ushort_t*)alloc((size_t)NREL * HD_ * D_ * 2);
  ushort_t* ft  = (ushort_t*)alloc((size_t)NREL * N_ * HD_ * 2);
  ushort_t* srb = (ushort_t*)alloc((size_t)768 * D_ * 2);
  ushort_t* bbn = (ushort_t*)alloc((size_t)VPAD * D_ * 2);

  hipMemsetAsync(d_ws, 0, (size_t)(zero_end - (char*)d_ws), stream);

  k_convert<<<1536, 256, 0, stream>>>(g1w, g2w, Wt);
  k_hv<<<N_ / 4, 256, 0, stream>>>(emb, iid, hv, hvb);
  k_ft<<<NREL * 640, 256, 0, stream>>>(hvb, Wt, g1b, g2b, ft);
  k_edge1<<<NREL * E_ / 4, 256, 0, stream>>>(ft, src, dst, g1pi, g2pi, ex, den_att);
  k_csr<<<NREL * E_ / 256, 256, 0, stream>>>(src, dst, cnt, slots);
  k_nodeout<<<NREL * N_, 128, 0, stream>>>(ft, ex, den_att, cnt, slots, src, dst, mh);
  k_combine<<<O_ * N_ / 4, 256, 0, stream>>>(hv, mh, h);
  k_pa<<<O_ * (N_ / 16), 128, 0, stream>>>(h, pos, qw, pid, tidv, aggd, tgt, coef);
  k_agg<<<O_ * B_, 128, 0, stream>>>(h, coef, srw, lasti, srb);
  k_bb<<<V_ / 4, 256, 0, stream>>>(emb, bbn);
  k_den<<<(VPAD / 128) * 4, 256, 0, stream>>>(srb, bbn, den_sm);
  k_w<<<3, 256, 0, stream>>>(alpha, den_sm, w_sm);
  k_out<<<(VPAD / 128) * 4, 256, 0, stream>>>(srb, bbn, w_sm, out);
}